// Round 12
// baseline (506.754 us; speedup 1.0000x reference)
//
#include <hip/hip_runtime.h>
#include <hip/hip_bf16.h>
#include <math.h>

#define V 32000
#define B 32
#define E 64
#define H 256
#define T 128
#define NROW (B*T)     // 4096 rows, row = t*B + b
#define NC 128         // vocab cols per block (logits)
#define NVB (V/NC)     // 250

typedef __attribute__((ext_vector_type(8))) short bf16x8;
typedef __attribute__((ext_vector_type(4))) float f32x4;
typedef __attribute__((ext_vector_type(8))) unsigned short u16x8;

// ws layout (float offsets)
#define OFF_XS   0                          // xs fp32 [T*B][E]              1MB
#define OFF_XW   (OFF_XS + NROW*E)          // xwq bf16 8MB; WoT bf16 16MB aliases after recur
#define OFF_HB   (OFF_XW + NROW*4*H)        // hb bf16 [t*B+b][k]            2MB
#define OFF_PS   (OFF_HB + NROW*H/2)        // ps fp32 [NVB][NROW]           4MB
#define OFF_TL   (OFF_PS + NVB*NROW)        // tl fp32 [NROW]
#define OFF_U8   (OFF_TL + NROW)            // UQ8 i8 [k4][j][g*4+kk]        256KB
#define OFF_SC   (OFF_U8 + H*H)             // per-gate scales, 4 floats
#define OFF_TGT  (OFF_SC + 16)              // tgtrow int [NROW]             16KB

static __device__ __forceinline__ unsigned short f2bf(float f) {
    union { float f; unsigned int u; } x; x.f = f;
    unsigned int r = x.u + 0x7fffu + ((x.u >> 16) & 1u);   // RNE
    return (unsigned short)(r >> 16);
}
static __device__ __forceinline__ float bf2f(unsigned short u) {
    union { unsigned int u; float f; } x; x.u = ((unsigned int)u) << 16; return x.f;
}
static __device__ __forceinline__ float sigmoidf_(float x) { return 1.f / (1.f + __expf(-x)); }
static __device__ __forceinline__ float tanhf_(float x)    { return 2.f / (1.f + __expf(-2.f * x)) - 1.f; }

#if defined(__has_builtin)
#if __has_builtin(__builtin_amdgcn_sdot4)
#define HAVE_SDOT4 1
#endif
#endif
static __device__ __forceinline__ int dot4i8(unsigned int a, unsigned int b, int c) {
#ifdef HAVE_SDOT4
    return __builtin_amdgcn_sdot4((int)a, (int)b, c, false);
#else
    c += (int)(char)(a)       * (int)(char)(b);
    c += (int)(char)(a >> 8)  * (int)(char)(b >> 8);
    c += (int)(char)(a >> 16) * (int)(char)(b >> 16);
    c += (int)(char)(a >> 24) * (int)(char)(b >> 24);
    return c;
#endif
}

// ------- kernel 1: embedding gather + target-row table + out zero -------------
__global__ void lstm_embed(const int* __restrict__ x, const float* __restrict__ emb,
                           const int* __restrict__ start, float* __restrict__ xs,
                           float* __restrict__ out, int* __restrict__ tgtrow) {
    int idx = blockIdx.x * 256 + threadIdx.x;
    if (idx == 0) out[0] = 0.f;               // zero accumulator each launch (graph-replay safe)
    if (idx < NROW) tgtrow[idx] = x[(idx & 31) * T + (idx >> 5)];   // tgt of row gr=t*32+b
    if (idx >= T * B * E) return;
    int t   = idx / (B * E);
    int rem = idx - t * (B * E);
    int b   = rem >> 6;
    int e   = rem & 63;
    int tok = (t == 0) ? start[0] : x[b * T + (t - 1)];
    xs[idx] = emb[tok * E + e];
}

// --- kernel 2: xwq[t*32+b][j][g] bf16 = (xs @ W_g + bias_g), block per t ------
__global__ __launch_bounds__(256) void lstm_xw(
        const float* __restrict__ xs, unsigned short* __restrict__ xwq,
        const float* __restrict__ Wi, const float* __restrict__ Wf,
        const float* __restrict__ Wog, const float* __restrict__ Wc,
        const float* __restrict__ bi, const float* __restrict__ bf,
        const float* __restrict__ bog, const float* __restrict__ bc) {
    __shared__ float xsl[32][65];
    const int t = blockIdx.x, tid = threadIdx.x;
    for (int i = tid; i < 32 * 64; i += 256) {
        int b = i >> 6, e = i & 63;
        xsl[b][e] = xs[(size_t)(t * 32 + b) * 64 + e];
    }
    __syncthreads();
    const int b = tid & 31, jg = tid >> 5;
    for (int jj = 0; jj < 32; ++jj) {
        const int j = jg * 32 + jj;
        float a0 = bi[j], a1 = bf[j], a2 = bog[j], a3 = bc[j];
        #pragma unroll 8
        for (int e = 0; e < E; ++e) {
            float xe = xsl[b][e];
            a0 += xe * Wi [e * H + j];
            a1 += xe * Wf [e * H + j];
            a2 += xe * Wog[e * H + j];
            a3 += xe * Wc [e * H + j];
        }
        ushort4 v;
        v.x = f2bf(a0); v.y = f2bf(a1); v.z = f2bf(a2); v.w = f2bf(a3);
        *(ushort4*)(xwq + ((size_t)(t * 32 + b) * 256 + j) * 4) = v;
    }
}

// ---- kernel 3: per-gate absmax of U (one block per gate, no atomics) ---------
__global__ __launch_bounds__(256) void lstm_umax(
        const float* __restrict__ Ui, const float* __restrict__ Uf,
        const float* __restrict__ Uog, const float* __restrict__ Uc,
        float* __restrict__ sc) {
    const int g = blockIdx.x;
    const float* U = (g == 0) ? Ui : (g == 1) ? Uf : (g == 2) ? Uog : Uc;
    float m = 0.f;
    for (int i = threadIdx.x; i < H * H; i += 256) m = fmaxf(m, fabsf(U[i]));
    __shared__ float red[256];
    red[threadIdx.x] = m;
    __syncthreads();
    for (int off = 128; off > 0; off >>= 1) {
        if (threadIdx.x < off) red[threadIdx.x] = fmaxf(red[threadIdx.x], red[threadIdx.x + off]);
        __syncthreads();
    }
    if (threadIdx.x == 0) sc[g] = fmaxf(red[0], 1e-20f);
}

// ---- kernel 4: U_g fp32 -> UQ8[k4][j] 16B = {gate g dword: bytes k4*4+0..3} --
__global__ __launch_bounds__(256) void lstm_uq8(
        const float* __restrict__ Ui, const float* __restrict__ Uf,
        const float* __restrict__ Uog, const float* __restrict__ Uc,
        const float* __restrict__ sc, unsigned int* __restrict__ UQ8) {
    const int idx = blockIdx.x * 256 + threadIdx.x;   // 64 k4 x 256 j
    const int k4 = idx >> 8, j = idx & 255;
    float inv[4] = { 127.f / sc[0], 127.f / sc[1], 127.f / sc[2], 127.f / sc[3] };
    const float* Ug[4] = { Ui, Uf, Uog, Uc };
    uint4 out;
    unsigned int* op = (unsigned int*)&out;
    #pragma unroll
    for (int g = 0; g < 4; ++g) {
        unsigned int w = 0;
        #pragma unroll
        for (int kk = 0; kk < 4; ++kk) {
            float v = Ug[g][(size_t)(k4 * 4 + kk) * H + j];
            int q = __float2int_rn(v * inv[g]);
            q = q > 127 ? 127 : (q < -127 ? -127 : q);
            w |= ((unsigned int)(q & 255)) << (kk * 8);
        }
        op[g] = w;
    }
    *(uint4*)(UQ8 + (size_t)idx * 4) = out;
}

// ---- kernel 5: recurrence — 32 independent blocks (1/batch row), i8 dot4 -----
// 1024 threads = 16 waves (4/SIMD). Thread (j = tid&255, q = tid>>8) computes
// the 4 gate partial dots of hidden unit j over k-quarter q (64 k) via
// v_dot4_i32_i8 on int8 U (256KB/step streamed from XCD L2, coalesced 1KB/wave
// per load) x int8 h (LDS, broadcast). 16KB LDS int4 reduce across quarters,
// then threads 0..255 do the pointwise LSTM (c in register), write h as bf16
// to hb and as int8 to the LDS ping-pong buffer. No inter-block communication.
__global__ __launch_bounds__(1024) void lstm_recur_i8(
        const unsigned short* __restrict__ xwq, const uint4* __restrict__ UQ8,
        const float* __restrict__ sc, unsigned short* __restrict__ hb) {
    __shared__ unsigned int hq8[2][64];     // int8 h, ping-pong, 4 k per dword
    __shared__ int4 red[4][256];            // per-quarter gate sums
    const int b = blockIdx.x, tid = threadIdx.x;
    const int j = tid & 255, q = tid >> 8;
    const float f0 = sc[0] * (1.f / 16129.f), f1 = sc[1] * (1.f / 16129.f);
    const float f2 = sc[2] * (1.f / 16129.f), f3 = sc[3] * (1.f / 16129.f);
    float c_ = 0.f;

    for (int t = 0; t < T; ++t) {
        if (t > 0) {
            const uint4* up = UQ8 + (size_t)(q * 16) * 256 + j;
            const unsigned int* hrow = hq8[t & 1] + q * 16;
            int a0 = 0, a1 = 0, a2 = 0, a3 = 0;
            #pragma unroll
            for (int m = 0; m < 16; ++m) {
                uint4 u = up[(size_t)m * 256];
                unsigned int hv = hrow[m];
                a0 = dot4i8(u.x, hv, a0);
                a1 = dot4i8(u.y, hv, a1);
                a2 = dot4i8(u.z, hv, a2);
                a3 = dot4i8(u.w, hv, a3);
            }
            red[q][j] = make_int4(a0, a1, a2, a3);
        }
        __syncthreads();
        if (tid < 256) {
            ushort4 xw = *(const ushort4*)(xwq + ((size_t)(t * 32 + b) * 256 + j) * 4);
            float pi = bf2f(xw.x), pf = bf2f(xw.y), po = bf2f(xw.z), pc = bf2f(xw.w);
            if (t > 0) {
                int4 r0 = red[0][j], r1 = red[1][j], r2 = red[2][j], r3 = red[3][j];
                pi += (float)(r0.x + r1.x + r2.x + r3.x) * f0;
                pf += (float)(r0.y + r1.y + r2.y + r3.y) * f1;
                po += (float)(r0.z + r1.z + r2.z + r3.z) * f2;
                pc += (float)(r0.w + r1.w + r2.w + r3.w) * f3;
            }
            c_ = sigmoidf_(pf) * c_ + sigmoidf_(pi) * tanhf_(pc);
            float h = sigmoidf_(po) * tanhf_(c_);
            hb[(size_t)(t * B + b) * H + j] = f2bf(h);
            ((char*)hq8[(t + 1) & 1])[j] = (char)__float2int_rn(h * 127.f);
        }
        __syncthreads();
    }
}

// -------- kernel 6: Wo [K=256][V] fp32  ->  WoT [V][K=256] bf16 (transpose) ---
__global__ __launch_bounds__(256) void lstm_wot(const float* __restrict__ Wo,
                                                unsigned short* __restrict__ WoT) {
    __shared__ unsigned short tle[64][65];
    const int n0 = blockIdx.x * 64, k0 = blockIdx.y * 64;
    const int tid = threadIdx.x;
    for (int i = tid; i < 64 * 64; i += 256) {
        int kk = i >> 6, nn = i & 63;
        tle[kk][nn] = f2bf(Wo[(size_t)(k0 + kk) * V + n0 + nn]);
    }
    __syncthreads();
    for (int c = tid; c < 512; c += 256) {
        int nn = c >> 3, kc = c & 7;
        u16x8 v;
        #pragma unroll
        for (int e = 0; e < 8; ++e) v[e] = tle[kc * 8 + e][nn];
        *(u16x8*)(WoT + (size_t)(n0 + nn) * H + k0 + kc * 8) = v;
    }
}

// ---- kernel 7: logits GEMM, B-tile in VGPRs, r0-loop, max-free fused softmax -
__global__ __launch_bounds__(512, 2) void lstm_logits_mfma(
        const unsigned short* __restrict__ hb, const unsigned short* __restrict__ WoT,
        const float* __restrict__ bo, const int* __restrict__ tgtrow,
        float* __restrict__ ps, float* __restrict__ tl) {
    __shared__ char a_s[65536];          // A tile 64KB, XOR-swizzled 512B rows
    __shared__ char b_s[65536];          // B stage 64KB
    __shared__ float s_red[4][128];      // per-colwave row sums
    __shared__ int   tgt_l[128];
    const int tid = threadIdx.x, lane = tid & 63, wid = tid >> 6;
    const int wr = wid >> 2, wc = wid & 3;          // 2 row-halves x 4 col-quarters
    const int lr = lane & 15, lg = lane >> 4;
    const int swz = lr & 7;
    const int vb = blockIdx.x * NC;

    {
        const uint4* srcB = (const uint4*)(WoT + (size_t)vb * H);
        for (int c = tid; c < 4096; c += 512) {
            int row = c >> 5, c16 = c & 31;
            *(uint4*)(b_s + row * 512 + ((c16 ^ (row & 7)) << 4)) = srcB[c];
        }
    }
    __syncthreads();
    bf16x8 Bf[2][8];
    {
        const char* bBase = b_s + (wc * 32 + lr) * 512;
        #pragma unroll
        for (int nf = 0; nf < 2; ++nf)
            #pragma unroll
            for (int ks = 0; ks < 8; ++ks)
                Bf[nf][ks] = *(const bf16x8*)(bBase + nf * 16 * 512 + (((ks * 4 + lg) ^ swz) << 4));
    }
    float bocol[2] = { bo[vb + wc * 32 + lr], bo[vb + wc * 32 + 16 + lr] };

    for (int rb = 0; rb < NROW / 128; ++rb) {
        {
            const uint4* srcA = (const uint4*)(hb + (size_t)rb * 128 * H);
            for (int c = tid; c < 4096; c += 512) {
                int row = c >> 5, c16 = c & 31;
                *(uint4*)(a_s + row * 512 + ((c16 ^ (row & 7)) << 4)) = srcA[c];
            }
            if (tid < 128) tgt_l[tid] = tgtrow[rb * 128 + tid];
        }
        __syncthreads();

        f32x4 acc[4][2] = {};
        const char* aBase = a_s + (wr * 64 + lr) * 512;
        #pragma unroll
        for (int ks = 0; ks < 8; ++ks) {
            bf16x8 a[4];
            #pragma unroll
            for (int mf = 0; mf < 4; ++mf)
                a[mf] = *(const bf16x8*)(aBase + mf * 16 * 512 + (((ks * 4 + lg) ^ swz) << 4));
            #pragma unroll
            for (int mf = 0; mf < 4; ++mf)
                #pragma unroll
                for (int nf = 0; nf < 2; ++nf)
                    acc[mf][nf] = __builtin_amdgcn_mfma_f32_16x16x32_bf16(a[mf], Bf[nf][ks], acc[mf][nf], 0, 0, 0);
        }

        const int col0 = vb + wc * 32 + lr, col1 = col0 + 16;
        #pragma unroll
        for (int mf = 0; mf < 4; ++mf)
            #pragma unroll
            for (int r = 0; r < 4; ++r) {
                const int row_l = wr * 64 + mf * 16 + lg * 4 + r;
                float v0 = acc[mf][0][r] + bocol[0];
                float v1 = acc[mf][1][r] + bocol[1];
                const int tg = tgt_l[row_l];
                if (tg == col0) tl[rb * 128 + row_l] = v0;
                if (tg == col1) tl[rb * 128 + row_l] = v1;
                float e = __expf(v0) + __expf(v1);
                e += __shfl_xor(e, 1); e += __shfl_xor(e, 2);
                e += __shfl_xor(e, 4); e += __shfl_xor(e, 8);
                if (lr == 0) s_red[wc][row_l] = e;
            }
        __syncthreads();
        if (tid < 128)
            ps[(size_t)blockIdx.x * NROW + rb * 128 + tid] =
                s_red[0][tid] + s_red[1][tid] + s_red[2][tid] + s_red[3][tid];
        __syncthreads();
    }
}

// ---------------- kernel 8: combine chunk sums, reduce NLL --------------------
__global__ __launch_bounds__(256) void lstm_lse(
        const float* __restrict__ ps, const float* __restrict__ tl,
        float* __restrict__ out) {
    const int row = blockIdx.x * 256 + threadIdx.x;
    float s = 0.f;
    for (int c = 0; c < NVB; ++c) s += ps[(size_t)c * NROW + row];
    float nll = logf(s) - tl[row];
    __shared__ float red[256];
    red[threadIdx.x] = nll;
    __syncthreads();
    for (int off = 128; off > 0; off >>= 1) {
        if (threadIdx.x < off) red[threadIdx.x] += red[threadIdx.x + off];
        __syncthreads();
    }
    if (threadIdx.x == 0) atomicAdd(out, red[0]);
}

extern "C" void kernel_launch(void* const* d_in, const int* in_sizes, int n_in,
                              void* d_out, int out_size, void* d_ws, size_t ws_size,
                              hipStream_t stream) {
    const int*   x     = (const int*)d_in[0];
    const float* emb   = (const float*)d_in[1];
    const float* Wi    = (const float*)d_in[2];
    const float* Ui    = (const float*)d_in[3];
    const float* bi    = (const float*)d_in[4];
    const float* Wf    = (const float*)d_in[5];
    const float* Uf    = (const float*)d_in[6];
    const float* bf    = (const float*)d_in[7];
    const float* Wog   = (const float*)d_in[8];
    const float* Uog   = (const float*)d_in[9];
    const float* bog   = (const float*)d_in[10];
    const float* Wc    = (const float*)d_in[11];
    const float* Uc    = (const float*)d_in[12];
    const float* bc    = (const float*)d_in[13];
    const float* Wo    = (const float*)d_in[14];
    const float* bo    = (const float*)d_in[15];
    const int*   start = (const int*)d_in[16];
    float* ws  = (float*)d_ws;
    float* out = (float*)d_out;

    float*          xs   = ws + OFF_XS;
    unsigned short* xwq  = (unsigned short*)(ws + OFF_XW);
    unsigned short* WoT  = (unsigned short*)(ws + OFF_XW);   // aliases xwq (dead after recur)
    unsigned short* hbf  = (unsigned short*)(ws + OFF_HB);
    float*          psB  = ws + OFF_PS;
    float*          tlB  = ws + OFF_TL;
    unsigned int*   UQ8  = (unsigned int*)(ws + OFF_U8);
    float*          scB  = ws + OFF_SC;
    int*            tgtr = (int*)(ws + OFF_TGT);

    lstm_embed <<<(T * B * E + 255) / 256, 256, 0, stream>>>(x, emb, start, xs, out, tgtr);
    lstm_xw    <<<T, 256, 0, stream>>>(xs, xwq, Wi, Wf, Wog, Wc, bi, bf, bog, bc);
    lstm_umax  <<<4, 256, 0, stream>>>(Ui, Uf, Uog, Uc, scB);
    lstm_uq8   <<<(H / 4) * H / 256, 256, 0, stream>>>(Ui, Uf, Uog, Uc, scB, UQ8);
    lstm_recur_i8<<<B, 1024, 0, stream>>>(xwq, (const uint4*)UQ8, scB, hbf);
    lstm_wot   <<<dim3(V / 64, H / 64), 256, 0, stream>>>(Wo, WoT);
    lstm_logits_mfma<<<NVB, 512, 0, stream>>>(hbf, WoT, bo, tgtr, psB, tlB);
    lstm_lse   <<<NROW / 256, 256, 0, stream>>>(psB, tlB, out);
}

// Round 13
// 438.434 us; speedup vs baseline: 1.1558x; 1.1558x over previous
//
#include <hip/hip_runtime.h>
#include <hip/hip_bf16.h>
#include <math.h>

#define V 32000
#define B 32
#define E 64
#define H 256
#define T 128
#define NROW (B*T)     // 4096 rows, row = t*B + b
#define NC 128         // vocab cols per block (logits)
#define NVB (V/NC)     // 250

typedef __attribute__((ext_vector_type(8))) short bf16x8;
typedef __attribute__((ext_vector_type(4))) float f32x4;
typedef __attribute__((ext_vector_type(8))) unsigned short u16x8;

// ws layout (float offsets)
#define OFF_XS   0                          // xs fp32 [T*B][E]              1MB
#define OFF_XW   (OFF_XS + NROW*E)          // xwq bf16 8MB; WoT bf16 16MB aliases after recur
#define OFF_HB   (OFF_XW + NROW*4*H)        // hb bf16 [t*B+b][k]            2MB
#define OFF_PS   (OFF_HB + NROW*H/2)        // ps fp32 [NVB][NROW]           4MB
#define OFF_TL   (OFF_PS + NVB*NROW)        // tl fp32 [NROW]
#define OFF_U8   (OFF_TL + NROW)            // UQ8 i8 [k4][j][g*4+kk]        256KB
#define OFF_SC   (OFF_U8 + H*H)             // per-gate scales, 4 floats
#define OFF_TGT  (OFF_SC + 16)              // tgtrow int [NROW]             16KB

static __device__ __forceinline__ unsigned short f2bf(float f) {
    union { float f; unsigned int u; } x; x.f = f;
    unsigned int r = x.u + 0x7fffu + ((x.u >> 16) & 1u);   // RNE
    return (unsigned short)(r >> 16);
}
static __device__ __forceinline__ float bf2f(unsigned short u) {
    union { unsigned int u; float f; } x; x.u = ((unsigned int)u) << 16; return x.f;
}
static __device__ __forceinline__ float sigmoidf_(float x) { return 1.f / (1.f + __expf(-x)); }
static __device__ __forceinline__ float tanhf_(float x)    { return 2.f / (1.f + __expf(-2.f * x)) - 1.f; }

#if defined(__has_builtin)
#if __has_builtin(__builtin_amdgcn_sdot4)
#define HAVE_SDOT4 1
#endif
#if __has_builtin(__builtin_amdgcn_global_load_lds)
#define HAVE_GLL 1
#endif
#endif
static __device__ __forceinline__ int dot4i8(unsigned int a, unsigned int b, int c) {
#ifdef HAVE_SDOT4
    return __builtin_amdgcn_sdot4((int)a, (int)b, c, false);
#else
    c += (int)(char)(a)       * (int)(char)(b);
    c += (int)(char)(a >> 8)  * (int)(char)(b >> 8);
    c += (int)(char)(a >> 16) * (int)(char)(b >> 16);
    c += (int)(char)(a >> 24) * (int)(char)(b >> 24);
    return c;
#endif
}
// async 16B global->LDS; builtin path: g per-lane, l wave-uniform (HW adds lane*16)
static __device__ __forceinline__ void stage16(const char* g, char* l, int lane) {
#ifdef HAVE_GLL
    __builtin_amdgcn_global_load_lds(
        (const __attribute__((address_space(1))) void*)g,
        (__attribute__((address_space(3))) void*)l, 16, 0, 0);
    (void)lane;
#else
    *(uint4*)(l + lane * 16) = *(const uint4*)g;
#endif
}

// ------- kernel 1: embedding gather + target-row table + out zero -------------
__global__ void lstm_embed(const int* __restrict__ x, const float* __restrict__ emb,
                           const int* __restrict__ start, float* __restrict__ xs,
                           float* __restrict__ out, int* __restrict__ tgtrow) {
    int idx = blockIdx.x * 256 + threadIdx.x;
    if (idx == 0) out[0] = 0.f;               // zero accumulator each launch (graph-replay safe)
    if (idx < NROW) tgtrow[idx] = x[(idx & 31) * T + (idx >> 5)];   // tgt of row gr=t*32+b
    if (idx >= T * B * E) return;
    int t   = idx / (B * E);
    int rem = idx - t * (B * E);
    int b   = rem >> 6;
    int e   = rem & 63;
    int tok = (t == 0) ? start[0] : x[b * T + (t - 1)];
    xs[idx] = emb[tok * E + e];
}

// --- kernel 2: xwq[t*32+b][j][g] bf16 = (xs @ W_g + bias_g), block per t ------
__global__ __launch_bounds__(256) void lstm_xw(
        const float* __restrict__ xs, unsigned short* __restrict__ xwq,
        const float* __restrict__ Wi, const float* __restrict__ Wf,
        const float* __restrict__ Wog, const float* __restrict__ Wc,
        const float* __restrict__ bi, const float* __restrict__ bf,
        const float* __restrict__ bog, const float* __restrict__ bc) {
    __shared__ float xsl[32][65];
    const int t = blockIdx.x, tid = threadIdx.x;
    for (int i = tid; i < 32 * 64; i += 256) {
        int b = i >> 6, e = i & 63;
        xsl[b][e] = xs[(size_t)(t * 32 + b) * 64 + e];
    }
    __syncthreads();
    const int b = tid & 31, jg = tid >> 5;
    for (int jj = 0; jj < 32; ++jj) {
        const int j = jg * 32 + jj;
        float a0 = bi[j], a1 = bf[j], a2 = bog[j], a3 = bc[j];
        #pragma unroll 8
        for (int e = 0; e < E; ++e) {
            float xe = xsl[b][e];
            a0 += xe * Wi [e * H + j];
            a1 += xe * Wf [e * H + j];
            a2 += xe * Wog[e * H + j];
            a3 += xe * Wc [e * H + j];
        }
        ushort4 v;
        v.x = f2bf(a0); v.y = f2bf(a1); v.z = f2bf(a2); v.w = f2bf(a3);
        *(ushort4*)(xwq + ((size_t)(t * 32 + b) * 256 + j) * 4) = v;
    }
}

// ---- kernel 3: per-gate absmax of U (one block per gate, no atomics) ---------
__global__ __launch_bounds__(256) void lstm_umax(
        const float* __restrict__ Ui, const float* __restrict__ Uf,
        const float* __restrict__ Uog, const float* __restrict__ Uc,
        float* __restrict__ sc) {
    const int g = blockIdx.x;
    const float* U = (g == 0) ? Ui : (g == 1) ? Uf : (g == 2) ? Uog : Uc;
    float m = 0.f;
    for (int i = threadIdx.x; i < H * H; i += 256) m = fmaxf(m, fabsf(U[i]));
    __shared__ float red[256];
    red[threadIdx.x] = m;
    __syncthreads();
    for (int off = 128; off > 0; off >>= 1) {
        if (threadIdx.x < off) red[threadIdx.x] = fmaxf(red[threadIdx.x], red[threadIdx.x + off]);
        __syncthreads();
    }
    if (threadIdx.x == 0) sc[g] = fmaxf(red[0], 1e-20f);
}

// ---- kernel 4: U_g fp32 -> UQ8[k4][j] 16B = {gate g dword: bytes k4*4+0..3} --
__global__ __launch_bounds__(256) void lstm_uq8(
        const float* __restrict__ Ui, const float* __restrict__ Uf,
        const float* __restrict__ Uog, const float* __restrict__ Uc,
        const float* __restrict__ sc, unsigned int* __restrict__ UQ8) {
    const int idx = blockIdx.x * 256 + threadIdx.x;   // 64 k4 x 256 j
    const int k4 = idx >> 8, j = idx & 255;
    float inv[4] = { 127.f / sc[0], 127.f / sc[1], 127.f / sc[2], 127.f / sc[3] };
    const float* Ug[4] = { Ui, Uf, Uog, Uc };
    uint4 out;
    unsigned int* op = (unsigned int*)&out;
    #pragma unroll
    for (int g = 0; g < 4; ++g) {
        unsigned int w = 0;
        #pragma unroll
        for (int kk = 0; kk < 4; ++kk) {
            float v = Ug[g][(size_t)(k4 * 4 + kk) * H + j];
            int q = __float2int_rn(v * inv[g]);
            q = q > 127 ? 127 : (q < -127 ? -127 : q);
            w |= ((unsigned int)(q & 255)) << (kk * 8);
        }
        op[g] = w;
    }
    *(uint4*)(UQ8 + (size_t)idx * 4) = out;
}

// ---- kernel 5: recurrence — 32 independent blocks (1/batch row), i8 dot4 -----
__global__ __launch_bounds__(1024) void lstm_recur_i8(
        const unsigned short* __restrict__ xwq, const uint4* __restrict__ UQ8,
        const float* __restrict__ sc, unsigned short* __restrict__ hb) {
    __shared__ unsigned int hq8[2][64];     // int8 h, ping-pong, 4 k per dword
    __shared__ int4 red[4][256];            // per-quarter gate sums
    const int b = blockIdx.x, tid = threadIdx.x;
    const int j = tid & 255, q = tid >> 8;
    const float f0 = sc[0] * (1.f / 16129.f), f1 = sc[1] * (1.f / 16129.f);
    const float f2 = sc[2] * (1.f / 16129.f), f3 = sc[3] * (1.f / 16129.f);
    float c_ = 0.f;

    for (int t = 0; t < T; ++t) {
        if (t > 0) {
            const uint4* up = UQ8 + (size_t)(q * 16) * 256 + j;
            const unsigned int* hrow = hq8[t & 1] + q * 16;
            int a0 = 0, a1 = 0, a2 = 0, a3 = 0;
            #pragma unroll
            for (int m = 0; m < 16; ++m) {
                uint4 u = up[(size_t)m * 256];
                unsigned int hv = hrow[m];
                a0 = dot4i8(u.x, hv, a0);
                a1 = dot4i8(u.y, hv, a1);
                a2 = dot4i8(u.z, hv, a2);
                a3 = dot4i8(u.w, hv, a3);
            }
            red[q][j] = make_int4(a0, a1, a2, a3);
        }
        __syncthreads();
        if (tid < 256) {
            ushort4 xw = *(const ushort4*)(xwq + ((size_t)(t * 32 + b) * 256 + j) * 4);
            float pi = bf2f(xw.x), pf = bf2f(xw.y), po = bf2f(xw.z), pc = bf2f(xw.w);
            if (t > 0) {
                int4 r0 = red[0][j], r1 = red[1][j], r2 = red[2][j], r3 = red[3][j];
                pi += (float)(r0.x + r1.x + r2.x + r3.x) * f0;
                pf += (float)(r0.y + r1.y + r2.y + r3.y) * f1;
                po += (float)(r0.z + r1.z + r2.z + r3.z) * f2;
                pc += (float)(r0.w + r1.w + r2.w + r3.w) * f3;
            }
            c_ = sigmoidf_(pf) * c_ + sigmoidf_(pi) * tanhf_(pc);
            float h = sigmoidf_(po) * tanhf_(c_);
            hb[(size_t)(t * B + b) * H + j] = f2bf(h);
            ((char*)hq8[(t + 1) & 1])[j] = (char)__float2int_rn(h * 127.f);
        }
        __syncthreads();
    }
}

// -------- kernel 6: Wo [K=256][V] fp32  ->  WoT [V][K=256] bf16 (transpose) ---
__global__ __launch_bounds__(256) void lstm_wot(const float* __restrict__ Wo,
                                                unsigned short* __restrict__ WoT) {
    __shared__ unsigned short tle[64][65];
    const int n0 = blockIdx.x * 64, k0 = blockIdx.y * 64;
    const int tid = threadIdx.x;
    for (int i = tid; i < 64 * 64; i += 256) {
        int kk = i >> 6, nn = i & 63;
        tle[kk][nn] = f2bf(Wo[(size_t)(k0 + kk) * V + n0 + nn]);
    }
    __syncthreads();
    for (int c = tid; c < 512; c += 256) {
        int nn = c >> 3, kc = c & 7;
        u16x8 v;
        #pragma unroll
        for (int e = 0; e < 8; ++e) v[e] = tle[kc * 8 + e][nn];
        *(u16x8*)(WoT + (size_t)(n0 + nn) * H + k0 + kc * 8) = v;
    }
}

// ---- kernel 7: logits GEMM — dbuf A via global_load_lds prefetch-ahead,
// 16 waves (4/SIMD), B in VGPRs, max-free fused softmax.
// LDS layout per tile: linear dest, PRE-SWIZZLED source (chunk c16 of row holds
// src chunk c16^(row&7)) so the swizzled ds_read below sees the original data
// (rule #21: inverse-swz source + swz read, involution).
__global__ __launch_bounds__(1024, 4) void lstm_logits_mfma(
        const unsigned short* __restrict__ hb, const unsigned short* __restrict__ WoT,
        const float* __restrict__ bo, const int* __restrict__ tgtrow,
        float* __restrict__ ps, float* __restrict__ tl) {
    __shared__ char ab0[65536];          // tile buffer 0 (B prologue, then A dbuf)
    __shared__ char ab1[65536];          // tile buffer 1
    __shared__ float s_red[4][132];      // per-colwave row sums (pad)
    const int tid = threadIdx.x, lane = tid & 63, wid = tid >> 6;   // 16 waves
    const int wr = wid >> 2, wc = wid & 3;          // 4 row-quarters x 4 col-quarters
    const int lr = lane & 15, lg = lane >> 4;
    const int swz = lr & 7;
    const int vb = blockIdx.x * NC;

    // stage one 64KB tile: 16 waves x 4 instr x (64 lanes x 16B)
    #define STAGE_TILE(dst_, srcbase_) { _Pragma("unroll") \
        for (int i_ = 0; i_ < 4; ++i_) { \
            int chunk_ = (wid * 4 + i_) * 64 + lane; \
            int row_ = chunk_ >> 5, c16_ = chunk_ & 31; \
            int srcc_ = c16_ ^ (row_ & 7); \
            stage16((const char*)(srcbase_) + row_ * 512 + srcc_ * 16, \
                    (dst_) + (wid * 4 + i_) * 1024, lane); \
        } }

    // ---- prologue: B slice -> ab0 -> registers ----
    STAGE_TILE(ab0, (const char*)(WoT + (size_t)vb * H));
    __syncthreads();                                  // drains vmcnt+lgkmcnt
    bf16x8 Bf[2][8];
    {
        const char* bBase = ab0 + (wc * 32 + lr) * 512;
        #pragma unroll
        for (int nf = 0; nf < 2; ++nf)
            #pragma unroll
            for (int ks = 0; ks < 8; ++ks)
                Bf[nf][ks] = *(const bf16x8*)(bBase + nf * 16 * 512 + (((ks * 4 + lg) ^ swz) << 4));
    }
    float bocol[2] = { bo[vb + wc * 32 + lr], bo[vb + wc * 32 + 16 + lr] };
    // A tile rb=0 -> ab1 (Bf reads drained by the syncthreads below)
    STAGE_TILE(ab1, (const char*)hb);
    __syncthreads();                                  // Bf consumed + A0 landed

    for (int rb = 0; rb < NROW / 128; ++rb) {
        char* curb = (rb & 1) ? ab0 : ab1;            // A[rb]
        char* nxtb = (rb & 1) ? ab1 : ab0;
        if (rb + 1 < NROW / 128)                      // prefetch A[rb+1] (async)
            STAGE_TILE(nxtb, (const char*)(hb + (size_t)(rb + 1) * 128 * H));

        f32x4 acc[2][2] = {};
        const char* aBase = curb + (wr * 32 + lr) * 512;
        #pragma unroll
        for (int ks = 0; ks < 8; ++ks) {
            const int co = ((ks * 4 + lg) ^ swz) << 4;
            bf16x8 a0 = *(const bf16x8*)(aBase + co);
            bf16x8 a1 = *(const bf16x8*)(aBase + 16 * 512 + co);
            acc[0][0] = __builtin_amdgcn_mfma_f32_16x16x32_bf16(a0, Bf[0][ks], acc[0][0], 0, 0, 0);
            acc[0][1] = __builtin_amdgcn_mfma_f32_16x16x32_bf16(a0, Bf[1][ks], acc[0][1], 0, 0, 0);
            acc[1][0] = __builtin_amdgcn_mfma_f32_16x16x32_bf16(a1, Bf[0][ks], acc[1][0], 0, 0, 0);
            acc[1][1] = __builtin_amdgcn_mfma_f32_16x16x32_bf16(a1, Bf[1][ks], acc[1][1], 0, 0, 0);
        }

        // ---- fused softmax partials, in-register ----
        const int col0 = vb + wc * 32 + lr, col1 = col0 + 16;
        #pragma unroll
        for (int mf = 0; mf < 2; ++mf)
            #pragma unroll
            for (int r = 0; r < 4; ++r) {
                const int row_l = wr * 32 + mf * 16 + lg * 4 + r;
                float v0 = acc[mf][0][r] + bocol[0];
                float v1 = acc[mf][1][r] + bocol[1];
                const int tg = tgtrow[rb * 128 + row_l];   // broadcast across lr
                if (tg == col0) tl[rb * 128 + row_l] = v0;
                if (tg == col1) tl[rb * 128 + row_l] = v1;
                float e = __expf(v0) + __expf(v1);
                e += __shfl_xor(e, 1); e += __shfl_xor(e, 2);
                e += __shfl_xor(e, 4); e += __shfl_xor(e, 8);
                if (lr == 0) s_red[wc][row_l] = e;
            }
        __syncthreads();                              // s_red ready (also drains prefetch)
        if (tid < 128)
            ps[(size_t)blockIdx.x * NROW + rb * 128 + tid] =
                s_red[0][tid] + s_red[1][tid] + s_red[2][tid] + s_red[3][tid];
        __syncthreads();                              // s_red consumed + A[rb+1] published
    }
    #undef STAGE_TILE
}

// ---------------- kernel 8: combine chunk sums, reduce NLL --------------------
__global__ __launch_bounds__(256) void lstm_lse(
        const float* __restrict__ ps, const float* __restrict__ tl,
        float* __restrict__ out) {
    const int row = blockIdx.x * 256 + threadIdx.x;
    float s = 0.f;
    for (int c = 0; c < NVB; ++c) s += ps[(size_t)c * NROW + row];
    float nll = logf(s) - tl[row];
    __shared__ float red[256];
    red[threadIdx.x] = nll;
    __syncthreads();
    for (int off = 128; off > 0; off >>= 1) {
        if (threadIdx.x < off) red[threadIdx.x] += red[threadIdx.x + off];
        __syncthreads();
    }
    if (threadIdx.x == 0) atomicAdd(out, red[0]);
}

extern "C" void kernel_launch(void* const* d_in, const int* in_sizes, int n_in,
                              void* d_out, int out_size, void* d_ws, size_t ws_size,
                              hipStream_t stream) {
    const int*   x     = (const int*)d_in[0];
    const float* emb   = (const float*)d_in[1];
    const float* Wi    = (const float*)d_in[2];
    const float* Ui    = (const float*)d_in[3];
    const float* bi    = (const float*)d_in[4];
    const float* Wf    = (const float*)d_in[5];
    const float* Uf    = (const float*)d_in[6];
    const float* bf    = (const float*)d_in[7];
    const float* Wog   = (const float*)d_in[8];
    const float* Uog   = (const float*)d_in[9];
    const float* bog   = (const float*)d_in[10];
    const float* Wc    = (const float*)d_in[11];
    const float* Uc    = (const float*)d_in[12];
    const float* bc    = (const float*)d_in[13];
    const float* Wo    = (const float*)d_in[14];
    const float* bo    = (const float*)d_in[15];
    const int*   start = (const int*)d_in[16];
    float* ws  = (float*)d_ws;
    float* out = (float*)d_out;

    float*          xs   = ws + OFF_XS;
    unsigned short* xwq  = (unsigned short*)(ws + OFF_XW);
    unsigned short* WoT  = (unsigned short*)(ws + OFF_XW);   // aliases xwq (dead after recur)
    unsigned short* hbf  = (unsigned short*)(ws + OFF_HB);
    float*          psB  = ws + OFF_PS;
    float*          tlB  = ws + OFF_TL;
    unsigned int*   UQ8  = (unsigned int*)(ws + OFF_U8);
    float*          scB  = ws + OFF_SC;
    int*            tgtr = (int*)(ws + OFF_TGT);

    lstm_embed <<<(T * B * E + 255) / 256, 256, 0, stream>>>(x, emb, start, xs, out, tgtr);
    lstm_xw    <<<T, 256, 0, stream>>>(xs, xwq, Wi, Wf, Wog, Wc, bi, bf, bog, bc);
    lstm_umax  <<<4, 256, 0, stream>>>(Ui, Uf, Uog, Uc, scB);
    lstm_uq8   <<<(H / 4) * H / 256, 256, 0, stream>>>(Ui, Uf, Uog, Uc, scB, UQ8);
    lstm_recur_i8<<<B, 1024, 0, stream>>>(xwq, (const uint4*)UQ8, scB, hbf);
    lstm_wot   <<<dim3(V / 64, H / 64), 256, 0, stream>>>(Wo, WoT);
    lstm_logits_mfma<<<NVB, 1024, 0, stream>>>(hbf, WoT, bo, tgtr, psB, tlB);
    lstm_lse   <<<NROW / 256, 256, 0, stream>>>(psB, tlB, out);
}